// Round 2
// baseline (275.390 us; speedup 1.0000x reference)
//
#include <hip/hip_runtime.h>
#include <math.h>

// ---------------------------------------------------------------------------
// TemporalGCN: 2-layer LSTM (per-node sequences) -> 2 GCN rounds -> edge MLP.
//
// R10: R9 post-mortem showed k_lstm_fused is LDS-return-path bound: 1536
// wave-uniform ds_read_b128 per CU per phase through the single per-CU DS
// pipe (~10cyc each) = 15.4K cyc/phase == measured 15.6K. Even broadcast
// b128 reads push 16B x 64 lanes through the 128B/clk crossbar.
// Fix: broadcast h via SGPRs (v_readlane -> v_fmac v,s,v), h kept
// lane-distributed in REGISTERS (lane k = unit k), replicated per wave:
//   A waves (tid<256): thread j holds Whh0[j] AND Wih1[j]; computes L0 gate
//     j of step t and L1 x-proj xv(t-1) SHARING the same 64 readlanes of h0.
//   B waves: thread j holds Whh1[j]; a0 = xv from LDS (1 b32/seq), dot over
//     readlanes of h1 (own register copy).
//   c/h updates done redundantly per wave on lane-owned state (4 b32
//     gate reads/seq, conflict-free). h never round-trips through LDS.
// One barrier per phase (double-buffered g0/g1/x1 by parity), 14 phases.
// DS per CU per phase: ~1536 b128 -> ~400 b32.
//
// Bit-exactness: all accumulation expressions replicated verbatim from R9
// (quarter-split a0..a3 float4 dot, ascending-k fmaf chain + single bias
// add, c = fv*c + iv*gv) -> absmax 0.0 preserved.
// ---------------------------------------------------------------------------

#define Hd   64
#define Ed   5
#define Fd   6
#define Bd   8
#define Wd   12
#define Nd   200
#define NSEQ (Bd*Nd)        // 1600 sequences (b,n)
#define NG   (4*Hd)         // 256 gate rows
#define SEQPB 8             // sequences per fused-LSTM block (200 % 8 == 0)
#define LNEPS 1e-5f

__device__ __forceinline__ float sigm(float x) { return 1.0f / (1.0f + __expf(-x)); }
__device__ __forceinline__ float tanh_fast(float x) {
  float ax = fabsf(x);
  float t  = __expf(-2.0f * ax);
  float r  = (1.0f - t) / (1.0f + t);
  return copysignf(r, x);
}
// Broadcast lane l's value of v to all lanes via SGPR (VALU pipe, not DS).
__device__ __forceinline__ float rdl(float v, int l) {
  return __int_as_float(__builtin_amdgcn_readlane(__float_as_int(v), l));
}

// --------------------------------------------------------------------------
// Prep: gcnWT[round][k][u]; epWT[round][e][u]; W1aT[k][n]=W1[n][k];
// W1bT[k][n]=W1[n][64+k]. Sizes: 8192 + 640 + 4096 + 4096 = 17024 elements.
__global__ __launch_bounds__(256) void k_prep(
    const float* __restrict__ gcn_W, const float* __restrict__ ep_W,
    const float* __restrict__ W1,
    float* __restrict__ gcnWT, float* __restrict__ epWT,
    float* __restrict__ W1aT, float* __restrict__ W1bT)
{
  int idx = blockIdx.x * 256 + threadIdx.x;
  if (idx < 8192) {                        // gcnWT[r][k][u] = gcn_W[r][u][k]
    int round = idx >> 12, rem = idx & 4095;
    int k = rem >> 6, u = rem & 63;
    gcnWT[idx] = gcn_W[round * 4096 + u * 64 + k];
  } else if (idx < 8832) {                 // epWT[r][e][u] = ep_W[r][u][e]
    int r0 = idx - 8192;
    int round = r0 / 320, rem = r0 % 320;
    int e = rem >> 6, u = rem & 63;
    epWT[r0] = ep_W[round * 320 + u * Ed + e];
  } else if (idx < 12928) {                // W1aT[k][n] = W1[n][k]
    int r0 = idx - 8832;
    int k = r0 >> 6, n = r0 & 63;
    W1aT[r0] = W1[n * 133 + k];
  } else if (idx < 17024) {                // W1bT[k][n] = W1[n][64+k]
    int r0 = idx - 12928;
    int k = r0 >> 6, n = r0 & 63;
    W1bT[r0] = W1[n * 133 + 64 + k];
  }
}

// --------------------------------------------------------------------------
// Fused 2-layer LSTM, SGPR-broadcast edition. 200 blocks x 512 threads,
// 8 seqs/block, ~1 block/CU (VGPR-weight excludes a second block).
// Phase t in [0,13]: A computes L0 step t (t<12) + xv(t-1) (t>=1);
//                    B computes L1 step t-2 (t>=2).
__global__ __launch_bounds__(512) void k_lstm_fused(
    const float* __restrict__ nf,                       // (B,W,N,F)
    const float* __restrict__ Wih0, const float* __restrict__ Whh0,
    const float* __restrict__ bih0, const float* __restrict__ bhh0,
    const float* __restrict__ Wih1, const float* __restrict__ Whh1,
    const float* __restrict__ bih1, const float* __restrict__ bhh1,
    float* __restrict__ hout)                           // (NSEQ, H)
{
  __shared__ float x_sh[SEQPB][Wd * Fd];     // 576
  __shared__ float g0_sh[2][SEQPB][NG];      // 16 KB (post-activation L0)
  __shared__ float g1_sh[2][SEQPB][NG];      // 16 KB (post-activation L1)
  __shared__ float x1_sh[2][SEQPB][NG];      // 16 KB (xv = Wih1.y + bias1)

  const int tid  = threadIdx.x;
  const int seq0 = blockIdx.x * SEQPB;
  const int b    = seq0 / Nd;                // uniform (200 % 8 == 0)
  const int n0   = seq0 % Nd;

  for (int idx = tid; idx < SEQPB * Wd * Fd; idx += 512) {
    int s = idx / (Wd * Fd), r = idx - s * (Wd * Fd);
    int t = r / Fd, f = r - t * Fd;
    x_sh[s][r] = nf[((b * Wd + t) * Nd + (n0 + s)) * Fd + f];
  }

  const bool isA = (tid < 256);
  const int j    = tid & 255;                // gate row within this layer
  const int jt   = j >> 6;                   // 0=i,1=f,2=g,3=o (wave-uniform)
  const int lane = tid & 63;                 // owned unit (state partition)

  // Per-thread weights (registers).
  float4 wh[16];                             // Whh0 row j (A) / Whh1 row j (B)
  float4 wi1[16];                            // Wih1 row j (A only)
  float  wx[Fd];                             // Wih0 row j (A only)
  float  bias0 = 0.f, bias1 = 0.f;
  if (isA) {
    const float4* wr = (const float4*)(Whh0 + j * Hd);
    #pragma unroll
    for (int q = 0; q < 16; ++q) wh[q] = wr[q];
    #pragma unroll
    for (int f = 0; f < Fd; ++f) wx[f] = Wih0[j * Fd + f];
    bias0 = bih0[j] + bhh0[j];
    const float4* xr = (const float4*)(Wih1 + j * Hd);
    #pragma unroll
    for (int q = 0; q < 16; ++q) wi1[q] = xr[q];
    bias1 = bih1[j] + bhh1[j];
  } else {
    const float4* wr = (const float4*)(Whh1 + j * Hd);
    #pragma unroll
    for (int q = 0; q < 16; ++q) wh[q] = wr[q];
  }

  // Lane-owned state, replicated per wave: lane k holds h_s[k], c_s[k].
  // A waves: layer-0 state. B waves: layer-1 state.
  float hr[SEQPB], cr[SEQPB];
  #pragma unroll
  for (int s = 0; s < SEQPB; ++s) { hr[s] = 0.f; cr[s] = 0.f; }
  __syncthreads();

  for (int t = 0; t <= Wd + 1; ++t) {
    // ================= gate section (registers + read-only/parity LDS) ====
    if (isA) {
      if (t < Wd) {
        #pragma unroll
        for (int s = 0; s < SEQPB; ++s) {
          const float* xp = &x_sh[s][t * Fd];
          float a0 = bias0, a1 = 0.f, a2 = 0.f, a3 = 0.f;
          #pragma unroll
          for (int f = 0; f < Fd; ++f) a1 += xp[f] * wx[f];
          float xacc = 0.f;
          #pragma unroll
          for (int q = 0; q < 16; ++q) {
            float hx = rdl(hr[s], 4 * q + 0);
            float hy = rdl(hr[s], 4 * q + 1);
            float hz = rdl(hr[s], 4 * q + 2);
            float hw = rdl(hr[s], 4 * q + 3);
            float d = hx * wh[q].x + hy * wh[q].y + hz * wh[q].z + hw * wh[q].w;
            if ((q & 3) == 0) a0 += d; else if ((q & 3) == 1) a1 += d;
            else if ((q & 3) == 2) a2 += d; else a3 += d;
            // x-projection for L1 step t-1 shares the same readlanes.
            xacc = fmaf(hx, wi1[q].x, xacc);
            xacc = fmaf(hy, wi1[q].y, xacc);
            xacc = fmaf(hz, wi1[q].z, xacc);
            xacc = fmaf(hw, wi1[q].w, xacc);
          }
          float acc = (a0 + a1) + (a2 + a3);
          g0_sh[t & 1][s][j] = (jt == 2) ? tanh_fast(acc) : sigm(acc);
          if (t >= 1) x1_sh[t & 1][s][j] = xacc + bias1;
        }
      } else if (t == Wd) {                  // t==12: xv(11) only
        #pragma unroll
        for (int s = 0; s < SEQPB; ++s) {
          float xacc = 0.f;
          #pragma unroll
          for (int q = 0; q < 16; ++q) {
            float hx = rdl(hr[s], 4 * q + 0);
            float hy = rdl(hr[s], 4 * q + 1);
            float hz = rdl(hr[s], 4 * q + 2);
            float hw = rdl(hr[s], 4 * q + 3);
            xacc = fmaf(hx, wi1[q].x, xacc);
            xacc = fmaf(hy, wi1[q].y, xacc);
            xacc = fmaf(hz, wi1[q].z, xacc);
            xacc = fmaf(hw, wi1[q].w, xacc);
          }
          x1_sh[t & 1][s][j] = xacc + bias1;
        }
      }
    } else {
      if (t >= 2) {                          // L1 step t-2
        #pragma unroll
        for (int s = 0; s < SEQPB; ++s) {
          float a0 = x1_sh[(t - 1) & 1][s][j];   // xv(t-2), written phase t-1
          float a1 = 0.f, a2 = 0.f, a3 = 0.f;
          #pragma unroll
          for (int q = 0; q < 16; ++q) {
            float hx = rdl(hr[s], 4 * q + 0);
            float hy = rdl(hr[s], 4 * q + 1);
            float hz = rdl(hr[s], 4 * q + 2);
            float hw = rdl(hr[s], 4 * q + 3);
            float d = hx * wh[q].x + hy * wh[q].y + hz * wh[q].z + hw * wh[q].w;
            if ((q & 3) == 0) a0 += d; else if ((q & 3) == 1) a1 += d;
            else if ((q & 3) == 2) a2 += d; else a3 += d;
          }
          float acc = (a0 + a1) + (a2 + a3);
          g1_sh[t & 1][s][j] = (jt == 2) ? tanh_fast(acc) : sigm(acc);
        }
      }
    }
    __syncthreads();                         // the ONLY barrier per phase

    // ================= update section (lane-owned state, redundant/wave) ==
    if (isA) {
      if (t < Wd) {
        #pragma unroll
        for (int s = 0; s < SEQPB; ++s) {
          const float* gb = g0_sh[t & 1][s];
          float iv = gb[lane], fv = gb[64 + lane];
          float gv = gb[128 + lane], ov = gb[192 + lane];
          cr[s] = fv * cr[s] + iv * gv;
          hr[s] = ov * tanh_fast(cr[s]);
        }
      }
    } else {
      if (t >= 2) {
        #pragma unroll
        for (int s = 0; s < SEQPB; ++s) {
          const float* gb = g1_sh[t & 1][s];
          float iv = gb[lane], fv = gb[64 + lane];
          float gv = gb[128 + lane], ov = gb[192 + lane];
          cr[s] = fv * cr[s] + iv * gv;
          hr[s] = ov * tanh_fast(cr[s]);
        }
      }
    }
    // No second barrier: next phase's gate section touches only registers,
    // x_sh (read-only), and opposite-parity g/x1 buffers; cross-parity
    // write-after-read hazards are separated by the next phase's barrier.
  }

  // Final h1(11) -> hout, from the first B wave's register copy. Coalesced.
  if (tid >= 256 && tid < 320) {
    #pragma unroll
    for (int s = 0; s < SEQPB; ++s)
      hout[(seq0 + s) * Hd + lane] = hr[s];
  }
}

// --------------------------------------------------------------------------
// Fused per-row node pipeline: wsum -> GCN r0 -> GCN r1 -> u/v precompute.
// One block per row (b,i); 256 threads. adj/ef rows staged into LDS with
// COALESCED loads; all weight reads coalesced via the k_prep transposes.
__global__ __launch_bounds__(256) void k_node(
    const float* __restrict__ ef,    const float* __restrict__ adj,
    const float* __restrict__ h0,
    const float* __restrict__ gcnWT, const float* __restrict__ gcn_b,
    const float* __restrict__ epWT,  const float* __restrict__ ep_b,
    const float* __restrict__ ln_g,  const float* __restrict__ ln_b,
    const float* __restrict__ W1aT,  const float* __restrict__ W1bT,
    const float* __restrict__ b1,
    float* __restrict__ uu, float* __restrict__ vt)
{
  __shared__ float ef_sh[Nd * Ed];   // 1000: edge_last row (coalesced stage)
  __shared__ float adj_sh[Nd];       // 200
  __shared__ float red[4][6];
  __shared__ float w6[6];
  __shared__ float hcur[Hd];

  const int row = blockIdx.x;      // b*200+i
  const int b = row / Nd, i = row % Nd;
  const int tid = threadIdx.x;

  const float* efrow = ef + (size_t)(((b * Wd + (Wd - 1)) * Nd + i)) * (Nd * Ed);
  for (int idx = tid; idx < Nd * Ed; idx += 256) ef_sh[idx] = efrow[idx];
  const float* adjrow = adj + (b * Nd + i) * Nd;
  if (tid < Nd) adj_sh[tid] = adjrow[tid];
  if (tid < Hd) hcur[tid] = h0[row * Hd + tid];
  __syncthreads();

  // ---- wsum: p[e] = sum_j adj*edge[e], p[5] = sum_j adj (order as before)
  float p[6] = {0.f, 0.f, 0.f, 0.f, 0.f, 0.f};
  if (tid < Nd) {
    float a = adj_sh[tid];
    p[5] = a;
    #pragma unroll
    for (int k = 0; k < Ed; ++k) p[k] = a * ef_sh[tid * Ed + k];
  }
  #pragma unroll
  for (int k = 0; k < 6; ++k) {
    float v = p[k];
    for (int off = 32; off > 0; off >>= 1) v += __shfl_down(v, off);
    p[k] = v;
  }
  if ((tid & 63) == 0) {
    #pragma unroll
    for (int k = 0; k < 6; ++k) red[tid >> 6][k] = p[k];
  }
  __syncthreads();
  if (tid < 6)
    w6[tid] = red[0][tid] + red[1][tid] + red[2][tid] + red[3][tid];
  __syncthreads();

  // ---- 2 GCN rounds (wave 0; coalesced transposed-weight reads)
  const int u = tid & 63;
  #pragma unroll
  for (int round = 0; round < 2; ++round) {
    float hnew = 0.f;
    if (tid < 64) {
      const float* gwT = gcnWT + round * 4096;   // [k][u]
      const float* ewT = epWT  + round * 320;    // [e][u]
      float acc = gcn_b[round * Hd + u] + w6[5] * ep_b[round * Hd + u];
      #pragma unroll
      for (int e = 0; e < Ed; ++e) acc += w6[e] * ewT[e * 64 + u];
      #pragma unroll 8
      for (int k = 0; k < Hd; ++k) acc += hcur[k] * gwT[k * 64 + u];

      float mu = acc;
      #pragma unroll
      for (int off = 1; off < 64; off <<= 1) mu += __shfl_xor(mu, off);
      mu *= (1.f / 64.f);
      float d = acc - mu;
      float var = d * d;
      #pragma unroll
      for (int off = 1; off < 64; off <<= 1) var += __shfl_xor(var, off);
      var *= (1.f / 64.f);
      float v = d * rsqrtf(var + LNEPS) * ln_g[round * Hd + u] + ln_b[round * Hd + u];
      hnew = fmaxf(v, 0.f);
    }
    __syncthreads();               // all reads of hcur done
    if (tid < 64) hcur[tid] = hnew;
    __syncthreads();
  }

  // ---- u/v precompute (threads 0..127; coalesced transposed W1 reads)
  if (tid < 64) {
    float acc = b1[tid];
    #pragma unroll 8
    for (int k = 0; k < Hd; ++k) acc += hcur[k] * W1aT[k * 64 + tid];
    uu[row * Hd + tid] = acc;
  } else if (tid < 128) {
    const int n = tid - 64;
    float acc = 0.f;
    #pragma unroll 8
    for (int k = 0; k < Hd; ++k) acc += hcur[k] * W1bT[k * 64 + n];
    vt[n * NSEQ + row] = acc;
  }
}

// --------------------------------------------------------------------------
// Edge MLP: thread per edge. z1[64] lives in VGPRs; W1c/W2/W3/b2 have
// wave-uniform indices -> scalar-pipe loads, fmac v,s,v at VALU issue peak.
__global__ __launch_bounds__(256) void k_mlp(
    const float* __restrict__ ef,
    const float* __restrict__ u, const float* __restrict__ vt,
    const float* __restrict__ W1,
    const float* __restrict__ W2, const float* __restrict__ b2,
    const float* __restrict__ W3, const float* __restrict__ b3,
    float* __restrict__ out)
{
  const int idx = blockIdx.x * 256 + threadIdx.x;   // < 320000
  const int b   = idx / (Nd * Nd);
  const int rem = idx - b * Nd * Nd;
  const int i   = rem / Nd;
  const int jj  = rem - i * Nd;

  const float* e = ef + (((b * Wd + (Wd - 1)) * Nd + i) * Nd + jj) * Ed;
  float e5[Ed];
  #pragma unroll
  for (int q = 0; q < Ed; ++q) e5[q] = e[q];

  const float* ur = u + (b * Nd + i) * Hd;
  const int vcol = b * Nd + jj;

  float z1[64];
  #pragma unroll
  for (int k = 0; k < 64; ++k) {
    float acc = ur[k] + vt[k * NSEQ + vcol];
    const float* w1c = W1 + k * 133 + 128;      // uniform -> scalar loads
    #pragma unroll
    for (int q = 0; q < Ed; ++q) acc += e5[q] * w1c[q];
    z1[k] = fmaxf(acc, 0.f);
  }

  float logit = b3[0];
  #pragma unroll 4
  for (int o = 0; o < 32; ++o) {
    float a0 = b2[o], a1 = 0.f, a2 = 0.f, a3 = 0.f;
    const float* w2 = W2 + o * 64;              // uniform -> scalar loads
    #pragma unroll
    for (int k = 0; k < 64; k += 4) {
      a0 += w2[k]     * z1[k];
      a1 += w2[k + 1] * z1[k + 1];
      a2 += w2[k + 2] * z1[k + 2];
      a3 += w2[k + 3] * z1[k + 3];
    }
    float z2 = fmaxf((a0 + a1) + (a2 + a3), 0.f);
    logit += W3[o] * z2;
  }
  out[idx] = 1.f / (1.f + __expf(-logit));
}

// --------------------------------------------------------------------------
extern "C" void kernel_launch(void* const* d_in, const int* in_sizes, int n_in,
                              void* d_out, int out_size, void* d_ws, size_t ws_size,
                              hipStream_t stream) {
  (void)in_sizes; (void)n_in; (void)out_size; (void)ws_size;
  const float* nf   = (const float*)d_in[0];
  const float* ef   = (const float*)d_in[1];
  const float* adj  = (const float*)d_in[2];
  const float* Wih0 = (const float*)d_in[3];
  const float* Whh0 = (const float*)d_in[4];
  const float* bih0 = (const float*)d_in[5];
  const float* bhh0 = (const float*)d_in[6];
  const float* Wih1 = (const float*)d_in[7];
  const float* Whh1 = (const float*)d_in[8];
  const float* bih1 = (const float*)d_in[9];
  const float* bhh1 = (const float*)d_in[10];
  const float* gcnW = (const float*)d_in[11];
  const float* gcnB = (const float*)d_in[12];
  const float* epW  = (const float*)d_in[13];
  const float* epB  = (const float*)d_in[14];
  const float* lnG  = (const float*)d_in[15];
  const float* lnB  = (const float*)d_in[16];
  const float* W1   = (const float*)d_in[17];
  const float* b1   = (const float*)d_in[18];
  const float* W2   = (const float*)d_in[19];
  const float* b2   = (const float*)d_in[20];
  const float* W3   = (const float*)d_in[21];
  const float* b3   = (const float*)d_in[22];
  float* out = (float*)d_out;

  // Workspace layout (floats).
  float* ws   = (float*)d_ws;
  float* h0   = ws;                        // 102,400
  float* uu   = h0   + 102400;             // 102,400
  float* vt   = uu   + 102400;             // 102,400
  float* gWT  = vt   + 102400;             // 8,192
  float* eWT  = gWT  + 8192;               // 640
  float* W1aT = eWT  + 640;                // 4,096
  float* W1bT = W1aT + 4096;               // 4,096

  k_prep      <<<67,        256, 0, stream>>>(gcnW, epW, W1, gWT, eWT, W1aT, W1bT);
  k_lstm_fused<<<NSEQ/SEQPB,512, 0, stream>>>(nf, Wih0, Whh0, bih0, bhh0,
                                              Wih1, Whh1, bih1, bhh1, h0);
  k_node      <<<1600,      256, 0, stream>>>(ef, adj, h0, gWT, gcnB, eWT, epB,
                                              lnG, lnB, W1aT, W1bT, b1, uu, vt);
  k_mlp       <<<1250,      256, 0, stream>>>(ef, uu, vt, W1, W2, b2, W3, b3, out);
}